// Round 6
// baseline (74.237 us; speedup 1.0000x reference)
//
#include <hip/hip_runtime.h>

// Problem constants (match reference setup_inputs exactly)
#define B_SZ     8
#define S_SZ     16384
#define D_SZ     512
#define BLK_TOK  128                 // selection_block_size
#define TOPK     16                  // top_k per block
#define NBLK     (S_SZ / BLK_TOK)    // 128 blocks per batch
#define NGBLK    (B_SZ * NBLK)       // 1024 (batch, block) pairs
#define BLK_PER_WG 2                 // blocks processed per workgroup

typedef float f32x4 __attribute__((ext_vector_type(4)));   // clang-native for NT store

// 512 WGs x 2 blocks each; phases software-pipelined by program order so the
// gather of block p overlaps the streaming of block p+1 (stores are
// fire-and-forget; rank bubble hidden behind next block's loads).
//  Phase 1: 8 waves score 16 tokens each, 4 rows in flight per iteration,
//           fp64 accumulate + 64-lane butterfly (bit-identical ordering to
//           the passing rounds -> identical selection -> absmax 0).
//  Phase 2: parallel rank-selection (thread i<128), matches jax.lax.top_k
//           descending order + lower-index tie-break.
//  Phase 3: gather with non-temporal stores (out never re-read; preserve L2
//           for x).
__global__ __launch_bounds__(512, 8) void token_select_kernel(
    const float* __restrict__ x,
    const float* __restrict__ W,
    float* __restrict__ out)
{
    const int tid  = threadIdx.x;      // 0..511
    const int wave = tid >> 6;         // 0..7
    const int lane = tid & 63;

    __shared__ double s_score[BLK_TOK];   // 1 KiB
    __shared__ int    s_sel[TOPK];

    const float4* W4 = reinterpret_cast<const float4*>(W);
    const float4 w0 = W4[lane];
    const float4 w1 = W4[64 + lane];

    for (int p = 0; p < BLK_PER_WG; ++p) {
        const int gblk = blockIdx.x * BLK_PER_WG + p;   // 0..1023
        const int b    = gblk >> 7;                     // / NBLK
        const int blk  = gblk & (NBLK - 1);

        const float* xbase = x + ((size_t)b * S_SZ + (size_t)blk * BLK_TOK) * D_SZ;

        // ---- Phase 1: wave w scores tokens [w*16, w*16+16), 4 rows/iter. ----
        const int t0 = wave * 16;
        #pragma unroll
        for (int it = 0; it < 4; ++it) {
            const int t = t0 + it * 4;
            const float4* r0 = reinterpret_cast<const float4*>(xbase + (size_t)(t + 0) * D_SZ);
            const float4* r1 = reinterpret_cast<const float4*>(xbase + (size_t)(t + 1) * D_SZ);
            const float4* r2 = reinterpret_cast<const float4*>(xbase + (size_t)(t + 2) * D_SZ);
            const float4* r3 = reinterpret_cast<const float4*>(xbase + (size_t)(t + 3) * D_SZ);
            // 8 loads issued up front: 8 KB outstanding per wave
            const float4 a0 = r0[lane];
            const float4 a1 = r0[64 + lane];
            const float4 b0 = r1[lane];
            const float4 b1 = r1[64 + lane];
            const float4 c0 = r2[lane];
            const float4 c1 = r2[64 + lane];
            const float4 d0 = r3[lane];
            const float4 d1 = r3[64 + lane];

            double accA = (double)a0.x * (double)w0.x + (double)a0.y * (double)w0.y
                        + (double)a0.z * (double)w0.z + (double)a0.w * (double)w0.w
                        + (double)a1.x * (double)w1.x + (double)a1.y * (double)w1.y
                        + (double)a1.z * (double)w1.z + (double)a1.w * (double)w1.w;
            double accB = (double)b0.x * (double)w0.x + (double)b0.y * (double)w0.y
                        + (double)b0.z * (double)w0.z + (double)b0.w * (double)w0.w
                        + (double)b1.x * (double)w1.x + (double)b1.y * (double)w1.y
                        + (double)b1.z * (double)w1.z + (double)b1.w * (double)w1.w;
            double accC = (double)c0.x * (double)w0.x + (double)c0.y * (double)w0.y
                        + (double)c0.z * (double)w0.z + (double)c0.w * (double)w0.w
                        + (double)c1.x * (double)w1.x + (double)c1.y * (double)w1.y
                        + (double)c1.z * (double)w1.z + (double)c1.w * (double)w1.w;
            double accD = (double)d0.x * (double)w0.x + (double)d0.y * (double)w0.y
                        + (double)d0.z * (double)w0.z + (double)d0.w * (double)w0.w
                        + (double)d1.x * (double)w1.x + (double)d1.y * (double)w1.y
                        + (double)d1.z * (double)w1.z + (double)d1.w * (double)w1.w;

            // four independent 64-lane butterflies, interleaved
            #pragma unroll
            for (int m = 32; m >= 1; m >>= 1) {
                accA += __shfl_xor(accA, m, 64);
                accB += __shfl_xor(accB, m, 64);
                accC += __shfl_xor(accC, m, 64);
                accD += __shfl_xor(accD, m, 64);
            }
            if (lane == 0) {
                s_score[t + 0] = accA;
                s_score[t + 1] = accB;
                s_score[t + 2] = accC;
                s_score[t + 3] = accD;
            }
        }
        __syncthreads();

        // ---- Phase 2: parallel rank-selection (threads 0..127). ----
        if (tid < BLK_TOK) {
            const double mine = s_score[tid];
            int rank = 0;
            #pragma unroll 8
            for (int j = 0; j < BLK_TOK; ++j) {
                const double sj = s_score[j];   // uniform address -> LDS broadcast
                rank += (sj > mine) || (sj == mine && j < tid);
            }
            if (rank < TOPK) s_sel[rank] = tid;   // exactly 16 distinct ranks < 16
        }
        __syncthreads();

        // ---- Phase 3: gather. Wave w copies rows {w, w+8}; NT stores. ----
        // Next iteration's phase 1 follows immediately in program order, so
        // these stores/re-reads overlap the next block's read stream.
        float* outbase = out + ((size_t)gblk * TOPK) * D_SZ;
        #pragma unroll
        for (int r = wave; r < TOPK; r += 8) {
            const int idx = s_sel[r];
            const float4* src = reinterpret_cast<const float4*>(xbase + (size_t)idx * D_SZ);
            f32x4*        dst = reinterpret_cast<f32x4*>(outbase + (size_t)r * D_SZ);
            const float4 v0 = src[lane];
            const float4 v1 = src[64 + lane];
            const f32x4 nv0 = { v0.x, v0.y, v0.z, v0.w };
            const f32x4 nv1 = { v1.x, v1.y, v1.z, v1.w };
            __builtin_nontemporal_store(nv0, dst + lane);
            __builtin_nontemporal_store(nv1, dst + 64 + lane);
        }
        // No extra barrier needed: next phase-1 only writes s_score (rank
        // reads completed before the sync above), and s_sel is rewritten
        // only after the next phase-1's own __syncthreads().
    }
}

extern "C" void kernel_launch(void* const* d_in, const int* in_sizes, int n_in,
                              void* d_out, int out_size, void* d_ws, size_t ws_size,
                              hipStream_t stream) {
    const float* x = (const float*)d_in[0];   // [8, 16384, 512] fp32
    const float* W = (const float*)d_in[1];   // [1, 512] fp32
    // d_in[2] = bias (zeros; a constant shift never changes top-k ordering and
    // scores are not part of the output, so it is irrelevant).
    float* out = (float*)d_out;               // [8, 2048, 512] fp32

    token_select_kernel<<<dim3(NGBLK / BLK_PER_WG), dim3(512), 0, stream>>>(x, W, out);
}

// Round 7
// 57.119 us; speedup vs baseline: 1.2997x; 1.2997x over previous
//
#include <hip/hip_runtime.h>

// Problem constants (match reference setup_inputs exactly)
#define B_SZ     8
#define S_SZ     16384
#define D_SZ     512
#define BLK_TOK  128                 // selection_block_size
#define TOPK     16                  // top_k per block
#define NBLK     (S_SZ / BLK_TOK)    // 128 blocks per batch

typedef float f32x4 __attribute__((ext_vector_type(4)));   // clang-native for NT store

// One 512-thread WG (8 waves) per (batch, token-block). 1024 WGs = 4 WGs/CU
// = 32 waves/CU resident — measured sweet spot for the HBM stream (round-6's
// 2-blocks-per-WG variant halved this and regressed 57->74 us).
//  Phase 1: 8 waves score 16 tokens each, 4 rows in flight per iteration
//           (8 KB/wave outstanding), fp64 accumulate + 64-lane butterfly.
//  Phase 2: parallel rank-selection (thread i<128 counts scores above its
//           own), matching jax.lax.top_k descending + lower-index tie-break.
//  Phase 3: gather with non-temporal stores (out is never re-read; keep L2/L3
//           for x so the gather re-reads hit cache).
__global__ __launch_bounds__(512, 8) void token_select_kernel(
    const float* __restrict__ x,
    const float* __restrict__ W,
    float* __restrict__ out)
{
    const int blk  = blockIdx.x;       // 0..127
    const int b    = blockIdx.y;       // 0..7
    const int tid  = threadIdx.x;      // 0..511
    const int wave = tid >> 6;         // 0..7
    const int lane = tid & 63;

    __shared__ double s_score[BLK_TOK];   // 1 KiB
    __shared__ int    s_sel[TOPK];

    const float4* W4 = reinterpret_cast<const float4*>(W);
    const float4 w0 = W4[lane];
    const float4 w1 = W4[64 + lane];

    const float* xbase = x + ((size_t)b * S_SZ + (size_t)blk * BLK_TOK) * D_SZ;

    // ---- Phase 1: wave w scores tokens [w*16, w*16+16), 4 rows/iter. ----
    const int t0 = wave * 16;
    #pragma unroll
    for (int it = 0; it < 4; ++it) {
        const int t = t0 + it * 4;
        const float4* r0 = reinterpret_cast<const float4*>(xbase + (size_t)(t + 0) * D_SZ);
        const float4* r1 = reinterpret_cast<const float4*>(xbase + (size_t)(t + 1) * D_SZ);
        const float4* r2 = reinterpret_cast<const float4*>(xbase + (size_t)(t + 2) * D_SZ);
        const float4* r3 = reinterpret_cast<const float4*>(xbase + (size_t)(t + 3) * D_SZ);
        // 8 loads issued up front: 8 KB outstanding per wave
        const float4 a0 = r0[lane];
        const float4 a1 = r0[64 + lane];
        const float4 b0 = r1[lane];
        const float4 b1 = r1[64 + lane];
        const float4 c0 = r2[lane];
        const float4 c1 = r2[64 + lane];
        const float4 d0 = r3[lane];
        const float4 d1 = r3[64 + lane];

        double accA = (double)a0.x * (double)w0.x + (double)a0.y * (double)w0.y
                    + (double)a0.z * (double)w0.z + (double)a0.w * (double)w0.w
                    + (double)a1.x * (double)w1.x + (double)a1.y * (double)w1.y
                    + (double)a1.z * (double)w1.z + (double)a1.w * (double)w1.w;
        double accB = (double)b0.x * (double)w0.x + (double)b0.y * (double)w0.y
                    + (double)b0.z * (double)w0.z + (double)b0.w * (double)w0.w
                    + (double)b1.x * (double)w1.x + (double)b1.y * (double)w1.y
                    + (double)b1.z * (double)w1.z + (double)b1.w * (double)w1.w;
        double accC = (double)c0.x * (double)w0.x + (double)c0.y * (double)w0.y
                    + (double)c0.z * (double)w0.z + (double)c0.w * (double)w0.w
                    + (double)c1.x * (double)w1.x + (double)c1.y * (double)w1.y
                    + (double)c1.z * (double)w1.z + (double)c1.w * (double)w1.w;
        double accD = (double)d0.x * (double)w0.x + (double)d0.y * (double)w0.y
                    + (double)d0.z * (double)w0.z + (double)d0.w * (double)w0.w
                    + (double)d1.x * (double)w1.x + (double)d1.y * (double)w1.y
                    + (double)d1.z * (double)w1.z + (double)d1.w * (double)w1.w;

        // four independent 64-lane butterflies, interleaved
        #pragma unroll
        for (int m = 32; m >= 1; m >>= 1) {
            accA += __shfl_xor(accA, m, 64);
            accB += __shfl_xor(accB, m, 64);
            accC += __shfl_xor(accC, m, 64);
            accD += __shfl_xor(accD, m, 64);
        }
        if (lane == 0) {
            s_score[t + 0] = accA;
            s_score[t + 1] = accB;
            s_score[t + 2] = accC;
            s_score[t + 3] = accD;
        }
    }
    __syncthreads();

    // ---- Phase 2: parallel rank-selection (threads 0..127). ----
    if (tid < BLK_TOK) {
        const double mine = s_score[tid];
        int rank = 0;
        #pragma unroll 8
        for (int j = 0; j < BLK_TOK; ++j) {
            const double sj = s_score[j];   // uniform address -> LDS broadcast
            rank += (sj > mine) || (sj == mine && j < tid);
        }
        if (rank < TOPK) s_sel[rank] = tid;   // exactly 16 distinct ranks < 16
    }
    __syncthreads();

    // ---- Phase 3: gather. Wave w copies rows {w, w+8}; NT stores. ----
    float* outbase = out + (((size_t)b * NBLK + blk) * TOPK) * D_SZ;
    #pragma unroll
    for (int r = wave; r < TOPK; r += 8) {
        const int idx = s_sel[r];
        const float4* src = reinterpret_cast<const float4*>(xbase + (size_t)idx * D_SZ);
        f32x4*        dst = reinterpret_cast<f32x4*>(outbase + (size_t)r * D_SZ);
        const float4 v0 = src[lane];
        const float4 v1 = src[64 + lane];
        const f32x4 nv0 = { v0.x, v0.y, v0.z, v0.w };
        const f32x4 nv1 = { v1.x, v1.y, v1.z, v1.w };
        __builtin_nontemporal_store(nv0, dst + lane);
        __builtin_nontemporal_store(nv1, dst + 64 + lane);
    }
}

extern "C" void kernel_launch(void* const* d_in, const int* in_sizes, int n_in,
                              void* d_out, int out_size, void* d_ws, size_t ws_size,
                              hipStream_t stream) {
    const float* x = (const float*)d_in[0];   // [8, 16384, 512] fp32
    const float* W = (const float*)d_in[1];   // [1, 512] fp32
    // d_in[2] = bias (zeros; a constant shift never changes top-k ordering and
    // scores are not part of the output, so it is irrelevant).
    float* out = (float*)d_out;               // [8, 2048, 512] fp32

    token_select_kernel<<<dim3(NBLK, B_SZ), dim3(512), 0, stream>>>(x, W, out);
}